// Round 2
// baseline (75.546 us; speedup 1.0000x reference)
//
#include <hip/hip_runtime.h>
#include <float.h>

#define N_NODES 200000
#define D 256
#define HID 512
#define OUTD 2
#define NG 512

// ---------------------------------------------------------------------------
// Cooperative 64-ary lower bound: smallest i with a[i] >= v (may return n).
// All 64 lanes of the calling wave must be active.
// ---------------------------------------------------------------------------
__device__ __forceinline__ int lower_bound_64ary(const int* __restrict__ a, int n,
                                                 int v, int lane) {
    int lo = -1, hi = n;  // invariant: a[lo] < v (virtual a[-1]=-inf), a[hi] >= v (virtual a[n]=+inf)
    while (hi - lo > 1) {
        int len = hi - lo;                                      // >= 2
        int off = 1 + (int)(((long long)lane * (len - 1)) >> 6); // in [1, len-1]
        int p = lo + off;                                        // in (lo, hi)
        bool lt = a[p] < v;
        unsigned long long m = __ballot(lt);
        int cnt = __popcll(m);  // probes are nondecreasing -> lt lanes form a prefix
        int nlo = (cnt == 0) ? lo : lo + 1 + (int)(((long long)(cnt - 1) * (len - 1)) >> 6);
        int nhi = (cnt == 64) ? hi : lo + 1 + (int)(((long long)cnt * (len - 1)) >> 6);
        lo = nlo; hi = nhi;
    }
    return hi;
}

// ---------------------------------------------------------------------------
// Kernel 1: segment max pooling, bounds fused (binary search on sorted batch).
// One block (4 waves) per graph. Lane l owns float4 cols [4l,4l+4).
// ---------------------------------------------------------------------------
__global__ __launch_bounds__(256) void k_pool(const float* __restrict__ x,
                                              const int* __restrict__ batch,
                                              float* __restrict__ gp) {
    const int g    = blockIdx.x;
    const int lane = threadIdx.x & 63;
    const int wave = threadIdx.x >> 6;

    __shared__ int sb[2];
    if (wave < 2) {
        int r = lower_bound_64ary(batch, N_NODES, g + wave, lane);
        if (lane == 0) sb[wave] = r;
    }
    __syncthreads();
    const int r0 = sb[0];
    const int r1 = sb[1];

    float4 m = make_float4(-FLT_MAX, -FLT_MAX, -FLT_MAX, -FLT_MAX);
    const float* xc = x + (size_t)lane * 4;

    int r = r0 + wave;
    for (; r + 12 < r1; r += 16) {
        float4 v0 = *reinterpret_cast<const float4*>(xc + (size_t)r * D);
        float4 v1 = *reinterpret_cast<const float4*>(xc + (size_t)(r + 4) * D);
        float4 v2 = *reinterpret_cast<const float4*>(xc + (size_t)(r + 8) * D);
        float4 v3 = *reinterpret_cast<const float4*>(xc + (size_t)(r + 12) * D);
        m.x = fmaxf(m.x, fmaxf(fmaxf(v0.x, v1.x), fmaxf(v2.x, v3.x)));
        m.y = fmaxf(m.y, fmaxf(fmaxf(v0.y, v1.y), fmaxf(v2.y, v3.y)));
        m.z = fmaxf(m.z, fmaxf(fmaxf(v0.z, v1.z), fmaxf(v2.z, v3.z)));
        m.w = fmaxf(m.w, fmaxf(fmaxf(v0.w, v1.w), fmaxf(v2.w, v3.w)));
    }
    for (; r < r1; r += 4) {
        float4 v = *reinterpret_cast<const float4*>(xc + (size_t)r * D);
        m.x = fmaxf(m.x, v.x); m.y = fmaxf(m.y, v.y);
        m.z = fmaxf(m.z, v.z); m.w = fmaxf(m.w, v.w);
    }

    __shared__ float4 lds[4][64];
    lds[wave][lane] = m;
    __syncthreads();
    if (wave == 0) {
        float4 a = lds[0][lane], b = lds[1][lane], c = lds[2][lane], d = lds[3][lane];
        float4 o;
        o.x = fmaxf(fmaxf(a.x, b.x), fmaxf(c.x, d.x));
        o.y = fmaxf(fmaxf(a.y, b.y), fmaxf(c.y, d.y));
        o.z = fmaxf(fmaxf(a.z, b.z), fmaxf(c.z, d.z));
        o.w = fmaxf(fmaxf(a.w, b.w), fmaxf(c.w, d.w));
        if (r1 == r0) o = make_float4(0.f, 0.f, 0.f, 0.f);  // empty graph -> zeros
        *reinterpret_cast<float4*>(gp + (size_t)g * D + lane * 4) = o;
    }
}

// ---------------------------------------------------------------------------
// Kernel 2: 32x32-tile f32 GEMM, 64 threads (1 wave), 4x4 micro-tile,
// A staged TRANSPOSED so both operand reads are ds_read_b128.
// C = act(A[M,K] @ B[K,N] + bias), all row-major. K % 32 == 0.
// ---------------------------------------------------------------------------
template <int K, bool RELU>
__global__ __launch_bounds__(64) void k_gemm(const float* __restrict__ A,
                                             const float* __restrict__ B,
                                             const float* __restrict__ bias,
                                             float* __restrict__ C, int N) {
    __shared__ float AsT[32][36];  // AsT[k][m]
    __shared__ float Bs[32][36];   // Bs[k][n]
    const int t  = threadIdx.x;
    const int bm = blockIdx.y * 32;
    const int bn = blockIdx.x * 32;
    const int r  = t >> 1;        // 0..31
    const int h  = t & 1;         // 0..1 (16-element half)
    const int ty = t >> 3;        // 0..7 -> rows ty*4..ty*4+3
    const int tx = t & 7;         // 0..7 -> cols tx*4..tx*4+3

    float acc[4][4] = {};

    for (int k0 = 0; k0 < K; k0 += 32) {
        float4 a4[4], b4[4];
#pragma unroll
        for (int j = 0; j < 4; ++j) {
            a4[j] = *reinterpret_cast<const float4*>(A + (size_t)(bm + r) * K + k0 + h * 16 + j * 4);
            b4[j] = *reinterpret_cast<const float4*>(B + (size_t)(k0 + r) * N + bn + h * 16 + j * 4);
        }
        __syncthreads();
#pragma unroll
        for (int j = 0; j < 4; ++j) {
            AsT[h * 16 + j * 4 + 0][r] = a4[j].x;
            AsT[h * 16 + j * 4 + 1][r] = a4[j].y;
            AsT[h * 16 + j * 4 + 2][r] = a4[j].z;
            AsT[h * 16 + j * 4 + 3][r] = a4[j].w;
            *reinterpret_cast<float4*>(&Bs[r][h * 16 + j * 4]) = b4[j];
        }
        __syncthreads();
#pragma unroll
        for (int kk = 0; kk < 32; ++kk) {
            float4 a = *reinterpret_cast<const float4*>(&AsT[kk][ty * 4]);
            float4 b = *reinterpret_cast<const float4*>(&Bs[kk][tx * 4]);
            const float av[4] = {a.x, a.y, a.z, a.w};
            const float bv[4] = {b.x, b.y, b.z, b.w};
#pragma unroll
            for (int i = 0; i < 4; ++i)
#pragma unroll
                for (int j = 0; j < 4; ++j)
                    acc[i][j] += av[i] * bv[j];
        }
    }

    float4 bb = *reinterpret_cast<const float4*>(bias + bn + tx * 4);
    const float bvv[4] = {bb.x, bb.y, bb.z, bb.w};
#pragma unroll
    for (int i = 0; i < 4; ++i) {
        float4 v;
        v.x = acc[i][0] + bvv[0];
        v.y = acc[i][1] + bvv[1];
        v.z = acc[i][2] + bvv[2];
        v.w = acc[i][3] + bvv[3];
        if (RELU) {
            v.x = fmaxf(v.x, 0.f); v.y = fmaxf(v.y, 0.f);
            v.z = fmaxf(v.z, 0.f); v.w = fmaxf(v.w, 0.f);
        }
        *reinterpret_cast<float4*>(C + (size_t)(bm + ty * 4 + i) * N + bn + tx * 4) = v;
    }
}

// ---------------------------------------------------------------------------
// Kernel 3: final [512,HID] @ [HID,2] + b3. One wave per output element.
// ---------------------------------------------------------------------------
__global__ __launch_bounds__(256) void k_fc3(const float* __restrict__ h,
                                             const float* __restrict__ W,
                                             const float* __restrict__ b,
                                             float* __restrict__ out) {
    const int wave = threadIdx.x >> 6;
    const int lane = threadIdx.x & 63;
    const int e = blockIdx.x * 4 + wave;        // 0..NG*OUTD-1
    const int row = e >> 1, col = e & 1;
    float s = 0.f;
#pragma unroll
    for (int k = lane; k < HID; k += 64)
        s += h[(size_t)row * HID + k] * W[(size_t)k * OUTD + col];
#pragma unroll
    for (int off = 32; off; off >>= 1) s += __shfl_xor(s, off);
    if (lane == 0) out[e] = s + b[col];
}

// ---------------------------------------------------------------------------
extern "C" void kernel_launch(void* const* d_in, const int* in_sizes, int n_in,
                              void* d_out, int out_size, void* d_ws, size_t ws_size,
                              hipStream_t stream) {
    const float* x     = (const float*)d_in[0];
    const int*   batch = (const int*)d_in[1];
    const float* W1    = (const float*)d_in[2];
    const float* b1    = (const float*)d_in[3];
    const float* W2    = (const float*)d_in[4];
    const float* b2    = (const float*)d_in[5];
    const float* W3    = (const float*)d_in[6];
    const float* b3    = (const float*)d_in[7];
    float* out = (float*)d_out;

    char* ws = (char*)d_ws;
    float* gp = (float*)ws;                                   // 512*256 f32 = 512KB
    float* h1 = (float*)(ws + 512 * 1024);                    // 512*512 f32 = 1MB
    float* h2 = (float*)(ws + 512 * 1024 + 1024 * 1024);      // 512*512 f32 = 1MB

    k_pool<<<NG, 256, 0, stream>>>(x, batch, gp);
    k_gemm<D,   true ><<<dim3(HID / 32, NG / 32), 64, 0, stream>>>(gp, W1, b1, h1, HID);
    k_gemm<HID, true ><<<dim3(HID / 32, NG / 32), 64, 0, stream>>>(h1, W2, b2, h2, HID);
    k_fc3<<<NG * OUTD / 4, 256, 0, stream>>>(h2, W3, b3, out);
}

// Round 3
// 66.841 us; speedup vs baseline: 1.1302x; 1.1302x over previous
//
#include <hip/hip_runtime.h>
#include <float.h>

#define N_NODES 200000
#define D 256
#define HID 512
#define OUTD 2
#define NG 512

// ---------------------------------------------------------------------------
// Kernel 1: segment boundaries from sorted batch vector (one pass).
// row_start[g] = first i with batch[i] >= g; row_start[NG] = N.
// ---------------------------------------------------------------------------
__global__ void k_bounds(const int* __restrict__ batch, int* __restrict__ row_start, int n) {
    int i = blockIdx.x * blockDim.x + threadIdx.x;
    if (i >= n) return;
    int b  = batch[i];
    int bp = (i == 0) ? -1 : batch[i - 1];
    for (int g = bp + 1; g <= b; ++g) row_start[g] = i;
    if (i == n - 1) {
        for (int g = b + 1; g <= NG; ++g) row_start[g] = n;
    }
}

__device__ __forceinline__ float4 fmax4(float4 a, float4 b) {
    return make_float4(fmaxf(a.x, b.x), fmaxf(a.y, b.y), fmaxf(a.z, b.z), fmaxf(a.w, b.w));
}

// ---------------------------------------------------------------------------
// Kernel 2: fused pool + 3-layer MLP. One block per 2 graphs (grid = 256).
// Pool: lane owns float4 cols [4l,4l+4); 4 waves stride rows, 8-deep unroll.
// MLP: thread t owns output cols 2t,2t+1 for both rows; weights via float2
// coalesced loads (L2-resident); activations live in LDS (broadcast reads).
// ---------------------------------------------------------------------------
__global__ __launch_bounds__(256) void k_main(const float* __restrict__ x,
                                              const int* __restrict__ rs,
                                              const float* __restrict__ W1,
                                              const float* __restrict__ b1,
                                              const float* __restrict__ W2,
                                              const float* __restrict__ b2,
                                              const float* __restrict__ W3,
                                              const float* __restrict__ b3,
                                              float* __restrict__ out) {
    const int t    = threadIdx.x;
    const int lane = t & 63;
    const int wave = t >> 6;
    const int g0   = blockIdx.x * 2;

    __shared__ float g_row[2][D];     // pooled rows
    __shared__ float h1s[2][HID];
    __shared__ float h2s[2][HID];
    __shared__ float4 red[4][64];
    __shared__ float fin[4][4];

    // ---------------- pool both graphs ----------------
    const float* xc = x + (size_t)lane * 4;
#pragma unroll
    for (int gi = 0; gi < 2; ++gi) {
        const int r0 = rs[g0 + gi];
        const int r1 = rs[g0 + gi + 1];
        float4 m = make_float4(-FLT_MAX, -FLT_MAX, -FLT_MAX, -FLT_MAX);
        int r = r0 + wave;
        for (; r + 28 < r1; r += 32) {
            float4 v0 = *reinterpret_cast<const float4*>(xc + (size_t)(r)      * D);
            float4 v1 = *reinterpret_cast<const float4*>(xc + (size_t)(r + 4)  * D);
            float4 v2 = *reinterpret_cast<const float4*>(xc + (size_t)(r + 8)  * D);
            float4 v3 = *reinterpret_cast<const float4*>(xc + (size_t)(r + 12) * D);
            float4 v4 = *reinterpret_cast<const float4*>(xc + (size_t)(r + 16) * D);
            float4 v5 = *reinterpret_cast<const float4*>(xc + (size_t)(r + 20) * D);
            float4 v6 = *reinterpret_cast<const float4*>(xc + (size_t)(r + 24) * D);
            float4 v7 = *reinterpret_cast<const float4*>(xc + (size_t)(r + 28) * D);
            m = fmax4(m, fmax4(fmax4(fmax4(v0, v1), fmax4(v2, v3)),
                               fmax4(fmax4(v4, v5), fmax4(v6, v7))));
        }
        for (; r < r1; r += 4) {
            float4 v = *reinterpret_cast<const float4*>(xc + (size_t)r * D);
            m = fmax4(m, v);
        }
        __syncthreads();               // guard red[] reuse across gi
        red[wave][lane] = m;
        __syncthreads();
        if (wave == 0) {
            float4 o = fmax4(fmax4(red[0][lane], red[1][lane]),
                             fmax4(red[2][lane], red[3][lane]));
            if (r1 == r0) o = make_float4(0.f, 0.f, 0.f, 0.f);   // empty graph
            *reinterpret_cast<float4*>(&g_row[gi][lane * 4]) = o;
        }
    }
    __syncthreads();

    // ---------------- layer 1: [2,256] @ [256,512] + b1, relu ----------------
    {
        float a00 = 0.f, a01 = 0.f, a10 = 0.f, a11 = 0.f;
        const float* w = W1 + 2 * t;
#pragma unroll 8
        for (int k = 0; k < D; k += 4) {
            float4 ga = *reinterpret_cast<const float4*>(&g_row[0][k]);
            float4 gb = *reinterpret_cast<const float4*>(&g_row[1][k]);
            float2 w0 = *reinterpret_cast<const float2*>(w + (size_t)(k)     * HID);
            float2 w1 = *reinterpret_cast<const float2*>(w + (size_t)(k + 1) * HID);
            float2 w2 = *reinterpret_cast<const float2*>(w + (size_t)(k + 2) * HID);
            float2 w3 = *reinterpret_cast<const float2*>(w + (size_t)(k + 3) * HID);
            a00 += ga.x * w0.x; a01 += ga.x * w0.y; a10 += gb.x * w0.x; a11 += gb.x * w0.y;
            a00 += ga.y * w1.x; a01 += ga.y * w1.y; a10 += gb.y * w1.x; a11 += gb.y * w1.y;
            a00 += ga.z * w2.x; a01 += ga.z * w2.y; a10 += gb.z * w2.x; a11 += gb.z * w2.y;
            a00 += ga.w * w3.x; a01 += ga.w * w3.y; a10 += gb.w * w3.x; a11 += gb.w * w3.y;
        }
        float2 bb = *reinterpret_cast<const float2*>(b1 + 2 * t);
        *reinterpret_cast<float2*>(&h1s[0][2 * t]) =
            make_float2(fmaxf(a00 + bb.x, 0.f), fmaxf(a01 + bb.y, 0.f));
        *reinterpret_cast<float2*>(&h1s[1][2 * t]) =
            make_float2(fmaxf(a10 + bb.x, 0.f), fmaxf(a11 + bb.y, 0.f));
    }
    __syncthreads();

    // ---------------- layer 2: [2,512] @ [512,512] + b2, relu ----------------
    {
        float a00 = 0.f, a01 = 0.f, a10 = 0.f, a11 = 0.f;
        const float* w = W2 + 2 * t;
#pragma unroll 8
        for (int k = 0; k < HID; k += 4) {
            float4 ga = *reinterpret_cast<const float4*>(&h1s[0][k]);
            float4 gb = *reinterpret_cast<const float4*>(&h1s[1][k]);
            float2 w0 = *reinterpret_cast<const float2*>(w + (size_t)(k)     * HID);
            float2 w1 = *reinterpret_cast<const float2*>(w + (size_t)(k + 1) * HID);
            float2 w2 = *reinterpret_cast<const float2*>(w + (size_t)(k + 2) * HID);
            float2 w3 = *reinterpret_cast<const float2*>(w + (size_t)(k + 3) * HID);
            a00 += ga.x * w0.x; a01 += ga.x * w0.y; a10 += gb.x * w0.x; a11 += gb.x * w0.y;
            a00 += ga.y * w1.x; a01 += ga.y * w1.y; a10 += gb.y * w1.x; a11 += gb.y * w1.y;
            a00 += ga.z * w2.x; a01 += ga.z * w2.y; a10 += gb.z * w2.x; a11 += gb.z * w2.y;
            a00 += ga.w * w3.x; a01 += ga.w * w3.y; a10 += gb.w * w3.x; a11 += gb.w * w3.y;
        }
        float2 bb = *reinterpret_cast<const float2*>(b2 + 2 * t);
        *reinterpret_cast<float2*>(&h2s[0][2 * t]) =
            make_float2(fmaxf(a00 + bb.x, 0.f), fmaxf(a01 + bb.y, 0.f));
        *reinterpret_cast<float2*>(&h2s[1][2 * t]) =
            make_float2(fmaxf(a10 + bb.x, 0.f), fmaxf(a11 + bb.y, 0.f));
    }
    __syncthreads();

    // ---------------- layer 3: [2,512] @ [512,2] + b3 ----------------
    {
        // thread t handles k = 2t, 2t+1; W3[k][c] pairs -> one float4
        float4 w = *reinterpret_cast<const float4*>(W3 + 4 * t);
        float2 ha = *reinterpret_cast<const float2*>(&h2s[0][2 * t]);
        float2 hb = *reinterpret_cast<const float2*>(&h2s[1][2 * t]);
        float p00 = ha.x * w.x + ha.y * w.z;
        float p01 = ha.x * w.y + ha.y * w.w;
        float p10 = hb.x * w.x + hb.y * w.z;
        float p11 = hb.x * w.y + hb.y * w.w;
#pragma unroll
        for (int off = 32; off; off >>= 1) {
            p00 += __shfl_xor(p00, off);
            p01 += __shfl_xor(p01, off);
            p10 += __shfl_xor(p10, off);
            p11 += __shfl_xor(p11, off);
        }
        if (lane == 0) {
            fin[wave][0] = p00; fin[wave][1] = p01;
            fin[wave][2] = p10; fin[wave][3] = p11;
        }
        __syncthreads();
        if (t < 4) {   // t = (row<<1)|col
            float s = fin[0][t] + fin[1][t] + fin[2][t] + fin[3][t];
            out[(size_t)(g0 + (t >> 1)) * OUTD + (t & 1)] = s + b3[t & 1];
        }
    }
}

// ---------------------------------------------------------------------------
extern "C" void kernel_launch(void* const* d_in, const int* in_sizes, int n_in,
                              void* d_out, int out_size, void* d_ws, size_t ws_size,
                              hipStream_t stream) {
    const float* x     = (const float*)d_in[0];
    const int*   batch = (const int*)d_in[1];
    const float* W1    = (const float*)d_in[2];
    const float* b1    = (const float*)d_in[3];
    const float* W2    = (const float*)d_in[4];
    const float* b2    = (const float*)d_in[5];
    const float* W3    = (const float*)d_in[6];
    const float* b3    = (const float*)d_in[7];
    float* out = (float*)d_out;

    int* row_start = (int*)d_ws;   // NG+1 ints

    k_bounds<<<(N_NODES + 255) / 256, 256, 0, stream>>>(batch, row_start, N_NODES);
    k_main<<<NG / 2, 256, 0, stream>>>(x, row_start, W1, b1, W2, b2, W3, b3, out);
}